// Round 11
// baseline (76.602 us; speedup 1.0000x reference)
//
#include <hip/hip_runtime.h>
#include <math.h>

namespace {

constexpr int   kN      = 4096;
constexpr int   kThreads = 256;             // 4 waves/block, 4 queries/wave
constexpr int   kIters  = 9;                // bracket [0,32768] -> width 64 (d2 0.031)
constexpr float kM0     = 0.3f;
constexpr float kS      = 2048.f;           // d2 scale: 16*2048 = 32768 < f16 max
constexpr float kRootS  = 45.25483399593904f;  // sqrt(2048)

typedef _Float16 h2 __attribute__((ext_vector_type(2)));

__device__ __forceinline__ h2 pkrtz(float a, float b) {
    return __builtin_bit_cast(h2, __builtin_amdgcn_cvt_pkrtz(a, b));
}
__device__ __forceinline__ float rdl63(float x) {
    return __builtin_bit_cast(float, __builtin_amdgcn_readlane(__builtin_bit_cast(int, x), 63));
}
// ctrl/rmask as template params: __builtin_amdgcn_update_dpp requires ICEs.
template <int kCtrl, int kRmask>
__device__ __forceinline__ void dppStep2(float& x, float& y) {
    const int xi = __builtin_amdgcn_update_dpp(0, __builtin_bit_cast(int, x), kCtrl, kRmask, 0xf, true);
    const int yi = __builtin_amdgcn_update_dpp(0, __builtin_bit_cast(int, y), kCtrl, kRmask, 0xf, true);
    x += __builtin_bit_cast(float, xi);
    y += __builtin_bit_cast(float, yi);
}
// Two interleaved DPP wave-64 sums -> uniform scalars (VALU-pipe only).
__device__ __forceinline__ void waveSum2(float& x, float& y) {
    dppStep2<0x111, 0xf>(x, y);   // row_shr:1
    dppStep2<0x112, 0xf>(x, y);   // row_shr:2
    dppStep2<0x114, 0xf>(x, y);   // row_shr:4
    dppStep2<0x118, 0xf>(x, y);   // row_shr:8
    dppStep2<0x142, 0xa>(x, y);   // row_bcast15
    dppStep2<0x143, 0xc>(x, y);   // row_bcast31 -> lane63 = total
    x = rdl63(x);
    y = rdl63(y);
}
__device__ __forceinline__ float waveSum1(float x) {
    float y = 0.f;
    waveSum2(x, y);
    return x;
}

// ONE instruction for clamp01(m - d): VOP3P neg_lo/neg_hi on src1 + CLAMP.
__device__ __forceinline__ h2 subClamp01(h2 m, h2 d) {
    h2 r;
    asm("v_pk_add_f16 %0, %1, %2 neg_lo:[0,1] neg_hi:[0,1] clamp"
        : "=v"(r) : "v"(m), "v"(d));
    return r;
}

// Batch raw data (points, weights) is query-independent: load ONCE per wave
// (f16-packed, pre-scaled by sqrt(2048): spx/spy/ws = 96 VGPRs), then run 4
// queries per wave with d2 built from registers (4 pk-inst / 2 points) — no
// VMEM after setup. Queries processed as 2 interleaved pairs so the DPP
// reduce latency of one bisection hides under the other's VALU stream.
// Bisection mids are multiples of 64 <= 32768 -> exact f16; masks at lo are
// bitwise-consistent across passes, preserving T(lo) < wb <= T(hi).
__global__ __launch_bounds__(kThreads, 2)
void dtm_kernel(const float* __restrict__ input,   // (B, N, 2)
                const float* __restrict__ weight,  // (B, N)
                const float* __restrict__ grid,    // (N, 2)
                float* __restrict__ out,           // (B, N)
                int nq) {
    const int lane = threadIdx.x & 63;
    const int wave = threadIdx.x >> 6;
    const int wg   = blockIdx.x * 4 + wave;      // [0, 2048): 1024 waves/batch
    const int b    = wg >> 10;
    const int base = wg & 1023;
    if ((b << 12) >= nq) return;

    const float4* inp4 = (const float4*)(input + (size_t)b * kN * 2);
    const float4* wgt4 = (const float4*)(weight + (size_t)b * kN);

    const h2 one2 = h2{(_Float16)1.f, (_Float16)1.f};

    // Raw batch data, loaded once: lane owns points {4*(lane+64s)+k}.
    h2 spx[32], spy[32], ws[32];                 // 96 VGPRs
    float wl0 = 0.f, wl1 = 0.f;
#pragma unroll
    for (int s = 0; s < 16; ++s) {
        const int g = lane + 64 * s;
        const float4 wv = wgt4[g];
        const float4 pa = inp4[2 * g];           // pts 4g,4g+1: (x0,y0,x1,y1)
        const float4 pb = inp4[2 * g + 1];       // pts 4g+2,4g+3
        spx[2 * s]     = pkrtz(kRootS * pa.x, kRootS * pa.z);
        spy[2 * s]     = pkrtz(kRootS * pa.y, kRootS * pa.w);
        spx[2 * s + 1] = pkrtz(kRootS * pb.x, kRootS * pb.z);
        spy[2 * s + 1] = pkrtz(kRootS * pb.y, kRootS * pb.w);
        ws[2 * s]      = pkrtz(wv.x, wv.y);
        ws[2 * s + 1]  = pkrtz(wv.z, wv.w);
        wl0 = __builtin_amdgcn_fdot2(ws[2 * s],     one2, wl0, false);
        wl1 = __builtin_amdgcn_fdot2(ws[2 * s + 1], one2, wl1, false);
    }
    const float wb = kM0 * waveSum1(wl0 + wl1);  // shared by all 4 queries

    float* ob = out + (size_t)b * kN;

#pragma unroll
    for (int p = 0; p < 2; ++p) {                // 2 pairs of queries
        const int iA = base + (p << 11);         // base, base+2048
        const int iB = iA + 1024;                // base+1024, base+3072
        // Wave-uniform query coords -> scalar loads; scaled, f16-rounded once.
        const _Float16 gxA = (_Float16)(kRootS * grid[2 * iA]);
        const _Float16 gyA = (_Float16)(kRootS * grid[2 * iA + 1]);
        const _Float16 gxB = (_Float16)(kRootS * grid[2 * iB]);
        const _Float16 gyB = (_Float16)(kRootS * grid[2 * iB + 1]);
        const h2 gxA2 = h2{gxA, gxA}, gyA2 = h2{gyA, gyA};
        const h2 gxB2 = h2{gxB, gxB}, gyB2 = h2{gyB, gyB};

        // Build both queries' scaled d2 from registers (no memory).
        h2 dA[32], dB[32];                       // 64 VGPRs (scoped per pair)
#pragma unroll
        for (int g = 0; g < 32; ++g) {
            const h2 ax = gxA2 - spx[g], ay = gyA2 - spy[g];
            dA[g] = ay * ay + ax * ax;           // pk_mul + pk_fma
            const h2 bx = gxB2 - spx[g], by = gyB2 - spy[g];
            dB[g] = by * by + bx * bx;
        }

        // Interleaved bisections. Invariant per query: T(lo) < wb <= T(hi).
        float loA = 0.f, hiA = 32768.f, TloA = 0.f;
        float loB = 0.f, hiB = 32768.f, TloB = 0.f;
#pragma unroll
        for (int it = 0; it < kIters; ++it) {
            const float midA = 0.5f * (loA + hiA);
            const float midB = 0.5f * (loB + hiB);
            const _Float16 mAh = (_Float16)midA; // exact (multiple of 64)
            const _Float16 mBh = (_Float16)midB;
            const h2 mA2 = h2{mAh, mAh};
            const h2 mB2 = h2{mBh, mBh};
            float a0 = 0.f, a1 = 0.f, b0 = 0.f, b1 = 0.f;
#pragma unroll
            for (int g = 0; g < 32; g += 2) {
                const h2 tA0 = subClamp01(mA2, dA[g]);
                const h2 tA1 = subClamp01(mA2, dA[g + 1]);
                const h2 tB0 = subClamp01(mB2, dB[g]);
                const h2 tB1 = subClamp01(mB2, dB[g + 1]);
                a0 = __builtin_amdgcn_fdot2(ws[g],     tA0, a0, false);
                a1 = __builtin_amdgcn_fdot2(ws[g + 1], tA1, a1, false);
                b0 = __builtin_amdgcn_fdot2(ws[g],     tB0, b0, false);
                b1 = __builtin_amdgcn_fdot2(ws[g + 1], tB1, b1, false);
            }
            float TA = a0 + a1, TB = b0 + b1;
            waveSum2(TA, TB);
            if (TA >= wb) hiA = midA; else { loA = midA; TloA = TA; }
            if (TB >= wb) hiB = midB; else { loB = midB; TloB = TB; }
        }

        // Final pass: A-sums below lo with IDENTICAL masks; W comes as Tlo.
        {
            const _Float16 lAh = (_Float16)loA;  // exact
            const _Float16 lBh = (_Float16)loB;
            const h2 lA2 = h2{lAh, lAh};
            const h2 lB2 = h2{lBh, lBh};
            float A0 = 0.f, A1 = 0.f, B0 = 0.f, B1 = 0.f;
#pragma unroll
            for (int g = 0; g < 32; g += 2) {
                const h2 tA0 = subClamp01(lA2, dA[g]);
                const h2 tA1 = subClamp01(lA2, dA[g + 1]);
                const h2 tB0 = subClamp01(lB2, dB[g]);
                const h2 tB1 = subClamp01(lB2, dB[g + 1]);
                const h2 pA0 = dA[g] * ws[g];    // scaled d2*w <= 32768 < 65504
                const h2 pA1 = dA[g + 1] * ws[g + 1];
                const h2 pB0 = dB[g] * ws[g];
                const h2 pB1 = dB[g + 1] * ws[g + 1];
                A0 = __builtin_amdgcn_fdot2(pA0, tA0, A0, false);
                A1 = __builtin_amdgcn_fdot2(pA1, tA1, A1, false);
                B0 = __builtin_amdgcn_fdot2(pB0, tB0, B0, false);
                B1 = __builtin_amdgcn_fdot2(pB1, tB1, B1, false);
            }
            float AA = A0 + A1, AB = B0 + B1;
            waveSum2(AA, AB);
            if (lane == 0) {
                const float dtmA = (AA + hiA * (wb - TloA)) * (1.f / kS);
                const float dtmB = (AB + hiB * (wb - TloB)) * (1.f / kS);
                ob[iA] = sqrtf(fmaxf(dtmA, 0.f) / wb);
                ob[iB] = sqrtf(fmaxf(dtmB, 0.f) / wb);
            }
        }
    }
}

}  // namespace

extern "C" void kernel_launch(void* const* d_in, const int* in_sizes, int n_in,
                              void* d_out, int out_size, void* d_ws, size_t ws_size,
                              hipStream_t stream) {
    const float* input  = (const float*)d_in[0];   // (B, N, 2) f32
    const float* weight = (const float*)d_in[1];   // (B, N)    f32
    const float* grid   = (const float*)d_in[2];   // (N, 2)    f32
    float* out = (float*)d_out;                    // (B, N)    f32
    const int nq = out_size;                       // B * N = 8192
    // 4 queries/wave, 4 waves/block -> nq/16 blocks (512).
    const int blocks = (nq + 15) / 16;
    dtm_kernel<<<dim3(blocks), dim3(kThreads), 0, stream>>>(input, weight, grid, out, nq);
}